// Round 1
// baseline (727.116 us; speedup 1.0000x reference)
//
#include <hip/hip_runtime.h>
#include <stdint.h>

#define NN 4096
#define NEG_SLOPE 0.01f
#define BM 128
#define BN 128
#define BK 32

typedef __bf16 bf16x8 __attribute__((ext_vector_type(8)));
typedef float f32x4 __attribute__((ext_vector_type(4)));

static __device__ __forceinline__ uint32_t f2bf(float f) {
    uint32_t u = __float_as_uint(f);
    return (u + 0x7FFFu + ((u >> 16) & 1u)) >> 16;  // RNE to bf16
}
static __device__ __forceinline__ float bf2f(uint32_t h) {
    return __uint_as_float(h << 16);
}

// Fused GEMM M = W2 @ W1 (bf16 hi/lo split, 3 MFMA passes) with row-reduction
// epilogue: lacc[j] += sum_k min(lb0[k]*M[j,k], ub0[k]*M[j,k]); uacc analog.
__global__ __launch_bounds__(256, 2)
void gemm_bounds(const float* __restrict__ W2, const float* __restrict__ W1,
                 const float* __restrict__ lb0, const float* __restrict__ ub0,
                 float* __restrict__ lacc, float* __restrict__ uacc) {
    // LDS layout: [k-chunk q][row][8 contiguous k] -> 16B units; MFMA frag
    // reads are ds_read_b128, 2-way bank aliasing (free per m136).
    __shared__ uint16_t sAhi[4][BM][8];
    __shared__ uint16_t sAlo[4][BM][8];
    __shared__ uint16_t sBhi[4][BN][8];
    __shared__ uint16_t sBlo[4][BN][8];

    const int t = threadIdx.x;
    const int lane = t & 63;
    const int wave = t >> 6;
    const int waveRow = wave >> 1, waveCol = wave & 1;
    const int quad = lane >> 4, l15 = lane & 15;

    const int bRow = (blockIdx.x >> 5) * BM;   // M rows (j)
    const int bCol = (blockIdx.x & 31) * BN;   // M cols (k of output)

    // A staging: 4 passes; row = p*32 + (t>>3), 4 consecutive k at (t&7)*4
    const int aRow = t >> 3;
    const int aK4  = (t & 7) * 4;
    const int aQ   = aK4 >> 3;
    const int aE   = aK4 & 7;     // 0 or 4
    // B staging: fixed col n = t&127, 16 consecutive contraction rows
    const int bn     = t & 127;
    const int bihalf = t >> 7;

    f32x4 acc[4][4];
#pragma unroll
    for (int i = 0; i < 4; ++i)
#pragma unroll
        for (int j = 0; j < 4; ++j) acc[i][j] = (f32x4){0.f, 0.f, 0.f, 0.f};

    float aBuf[4][4];
    float bBuf[16];

    const int NT = NN / BK;  // 128 K-tiles

    // ---- prefetch tile 0 ----
#pragma unroll
    for (int p = 0; p < 4; ++p) {
        const float4 v = *(const float4*)&W2[(size_t)(bRow + p * 32 + aRow) * NN + aK4];
        aBuf[p][0] = v.x; aBuf[p][1] = v.y; aBuf[p][2] = v.z; aBuf[p][3] = v.w;
    }
#pragma unroll
    for (int ii = 0; ii < 16; ++ii)
        bBuf[ii] = W1[(size_t)(bihalf * 16 + ii) * NN + bCol + bn];

    for (int kt = 0; kt < NT; ++kt) {
        __syncthreads();  // previous compute done reading LDS
        // ---- convert + store staged tile ----
#pragma unroll
        for (int p = 0; p < 4; ++p) {
            uint32_t h[4], l[4];
#pragma unroll
            for (int e = 0; e < 4; ++e) {
                h[e] = f2bf(aBuf[p][e]);
                l[e] = f2bf(aBuf[p][e] - bf2f(h[e]));
            }
            uint2 hv = make_uint2(h[0] | (h[1] << 16), h[2] | (h[3] << 16));
            uint2 lv = make_uint2(l[0] | (l[1] << 16), l[2] | (l[3] << 16));
            *(uint2*)&sAhi[aQ][p * 32 + aRow][aE] = hv;
            *(uint2*)&sAlo[aQ][p * 32 + aRow][aE] = lv;
        }
#pragma unroll
        for (int c = 0; c < 2; ++c) {
            uint32_t h[8], l[8];
#pragma unroll
            for (int e = 0; e < 8; ++e) {
                float f = bBuf[c * 8 + e];
                h[e] = f2bf(f);
                l[e] = f2bf(f - bf2f(h[e]));
            }
            uint4 hv = make_uint4(h[0] | (h[1] << 16), h[2] | (h[3] << 16),
                                  h[4] | (h[5] << 16), h[6] | (h[7] << 16));
            uint4 lv = make_uint4(l[0] | (l[1] << 16), l[2] | (l[3] << 16),
                                  l[4] | (l[5] << 16), l[6] | (l[7] << 16));
            *(uint4*)&sBhi[bihalf * 2 + c][bn][0] = hv;
            *(uint4*)&sBlo[bihalf * 2 + c][bn][0] = lv;
        }
        __syncthreads();

        // ---- prefetch next tile (latency hidden behind MFMA section) ----
        if (kt + 1 < NT) {
            const int k0 = (kt + 1) * BK;
#pragma unroll
            for (int p = 0; p < 4; ++p) {
                const float4 v = *(const float4*)&W2[(size_t)(bRow + p * 32 + aRow) * NN + k0 + aK4];
                aBuf[p][0] = v.x; aBuf[p][1] = v.y; aBuf[p][2] = v.z; aBuf[p][3] = v.w;
            }
#pragma unroll
            for (int ii = 0; ii < 16; ++ii)
                bBuf[ii] = W1[(size_t)(k0 + bihalf * 16 + ii) * NN + bCol + bn];
        }

        // ---- MFMA on staged tile: hi*hi + hi*lo + lo*hi ----
        bf16x8 ah[4], al[4];
#pragma unroll
        for (int fr = 0; fr < 4; ++fr) {
            const int row = waveRow * 64 + fr * 16 + l15;
            ah[fr] = *(bf16x8*)&sAhi[quad][row][0];
            al[fr] = *(bf16x8*)&sAlo[quad][row][0];
        }
#pragma unroll
        for (int fc = 0; fc < 4; ++fc) {
            const int col = waveCol * 64 + fc * 16 + l15;
            bf16x8 bh = *(bf16x8*)&sBhi[quad][col][0];
            bf16x8 bl = *(bf16x8*)&sBlo[quad][col][0];
#pragma unroll
            for (int fr = 0; fr < 4; ++fr) {
                acc[fr][fc] = __builtin_amdgcn_mfma_f32_16x16x32_bf16(ah[fr], bh, acc[fr][fc], 0, 0, 0);
                acc[fr][fc] = __builtin_amdgcn_mfma_f32_16x16x32_bf16(ah[fr], bl, acc[fr][fc], 0, 0, 0);
                acc[fr][fc] = __builtin_amdgcn_mfma_f32_16x16x32_bf16(al[fr], bh, acc[fr][fc], 0, 0, 0);
            }
        }
    }

    // ---- fused epilogue: weighted row-reduction over this block's 128 cols ----
    float lbv[4], ubv[4];
#pragma unroll
    for (int fc = 0; fc < 4; ++fc) {
        const int col = bCol + waveCol * 64 + fc * 16 + l15;
        lbv[fc] = lb0[col];
        ubv[fc] = ub0[col];
    }
#pragma unroll
    for (int fr = 0; fr < 4; ++fr) {
#pragma unroll
        for (int r = 0; r < 4; ++r) {
            float ls = 0.f, us = 0.f;
#pragma unroll
            for (int fc = 0; fc < 4; ++fc) {
                const float m = acc[fr][fc][r];
                const float a = lbv[fc] * m, b = ubv[fc] * m;
                ls += fminf(a, b);
                us += fmaxf(a, b);
            }
            // C/D layout: col = lane&15, row = quad*4 + r (m89/m91). Sum the 16
            // columns across the low 4 lane bits (quad partition preserved).
#pragma unroll
            for (int mk = 1; mk < 16; mk <<= 1) {
                ls += __shfl_xor(ls, mk, 64);
                us += __shfl_xor(us, mk, 64);
            }
            if (l15 == 0) {
                const int row = bRow + waveRow * 64 + fr * 16 + quad * 4 + r;
                atomicAdd(&lacc[row], ls);
                atomicAdd(&uacc[row], us);
            }
        }
    }
}

// cint[j] = sum_i b1[i]*W2[j,i] + b2[j]
__global__ __launch_bounds__(256)
void cint_kernel(const float* __restrict__ W2, const float* __restrict__ b1,
                 const float* __restrict__ b2, float* __restrict__ cint) {
    const int j = blockIdx.x;
    const int t = threadIdx.x;
    float s = 0.f;
    for (int i = t; i < NN; i += 256) s += b1[i] * W2[(size_t)j * NN + i];
    for (int mk = 1; mk < 64; mk <<= 1) s += __shfl_xor(s, mk, 64);
    __shared__ float wsum[4];
    if ((t & 63) == 0) wsum[t >> 6] = s;
    __syncthreads();
    if (t == 0) cint[j] = wsum[0] + wsum[1] + wsum[2] + wsum[3] + b2[j];
}

// DeepPoly LeakyReLU relaxation + diagonal/intercept writes (off-diag zeroed by memset)
__global__ __launch_bounds__(256)
void final_kernel(const float* __restrict__ lacc, const float* __restrict__ uacc,
                  const float* __restrict__ cint, const float* __restrict__ ra,
                  float* __restrict__ out) {
    const int j = blockIdx.x * 256 + threadIdx.x;
    if (j >= NN) return;
    const float lb = lacc[j] + cint[j];
    const float ub = uacc[j] + cint[j];
    const float alpha = 1.f / (1.f + expf(-ra[j]));
    float s = (ub - lb * NEG_SLOPE) / (ub - lb);
    if (!(s == s)) s = 0.f;  // NaN -> 0 (ref semantics)
    const float inter = (1.f - s) * ub;
    const bool below = (ub <= 0.f);
    const bool above = (lb >= 0.f);
    const bool crossing = !(below || above);
    const float uslope = crossing ? s : (below ? NEG_SLOPE : 1.f);
    const float uinter = crossing ? inter : 0.f;
    const float v1 = below ? NEG_SLOPE : 1.f;
    const float v2 = crossing ? NEG_SLOPE : (below ? NEG_SLOPE : 1.f);
    const float lslope = alpha * v1 + (1.f - alpha) * v2;

    const size_t N2 = (size_t)NN * NN;
    out[(size_t)j * NN + j] = lslope;                 // diag(lslope)
    // lintercept row stays zero (memset)
    out[N2 + NN + (size_t)j * NN + j] = uslope;       // diag(uslope)
    out[2 * N2 + NN + j] = uinter;                    // uintercept
}

extern "C" void kernel_launch(void* const* d_in, const int* in_sizes, int n_in,
                              void* d_out, int out_size, void* d_ws, size_t ws_size,
                              hipStream_t stream) {
    const float* lb0 = (const float*)d_in[0];
    const float* ub0 = (const float*)d_in[1];
    const float* W1  = (const float*)d_in[2];
    const float* b1  = (const float*)d_in[3];
    const float* W2  = (const float*)d_in[4];
    const float* b2  = (const float*)d_in[5];
    const float* ra  = (const float*)d_in[6];
    float* out = (float*)d_out;

    float* lacc = (float*)d_ws;          // [N]
    float* uacc = lacc + NN;             // [N]
    float* cint = uacc + NN;             // [N]

    hipMemsetAsync(d_out, 0, (size_t)out_size * sizeof(float), stream);
    hipMemsetAsync(d_ws, 0, 2 * NN * sizeof(float), stream);

    cint_kernel<<<dim3(NN), dim3(256), 0, stream>>>(W2, b1, b2, cint);
    gemm_bounds<<<dim3(1024), dim3(256), 0, stream>>>(W2, W1, lb0, ub0, lacc, uacc);
    final_kernel<<<dim3(NN / 256), dim3(256), 0, stream>>>(lacc, uacc, cint, ra, out);
}

// Round 2
// 416.528 us; speedup vs baseline: 1.7457x; 1.7457x over previous
//
#include <hip/hip_runtime.h>
#include <stdint.h>

#define NN 4096
#define NEG_SLOPE 0.01f

typedef _Float16 f16x8 __attribute__((ext_vector_type(8)));
typedef _Float16 f16x4 __attribute__((ext_vector_type(4)));
typedef float f32x4 __attribute__((ext_vector_type(4)));

// async global->LDS, 16B per lane; LDS dest = wave-uniform base + lane*16
__device__ __forceinline__ void async_ld16(void* lds, const void* g) {
    __builtin_amdgcn_global_load_lds(
        (__attribute__((address_space(1))) const void*)(const void*)g,
        (__attribute__((address_space(3))) void*)lds, 16, 0, 0);
}

// ---------------------------------------------------------------------------
// Fused GEMM M = W2 @ W1 (pre-converted fp16 operands) with row-reduction
// epilogue: lacc[j] += sum_k min(lb0[k]*M[j,k], ub0[k]*M[j,k]); uacc analog.
// A = Ah[4096][4096] fp16 (row-major W2); B = Bt[4096][4096] fp16 (W1^T: Bt[n][k]).
// LDS tile layout forced by global_load_lds: sX[row][32] fp16, row = 64 B.
// XOR swizzle: global k-chunk q of row r is stored at slot q ^ ((r>>1)&3),
// chosen on the FETCH side (lane picks its global chunk) so frag ds_read_b128
// touches all 32 banks at 2 lanes/bank (free per m136).
// ---------------------------------------------------------------------------
__global__ __launch_bounds__(256, 4)
void gemm_bounds(const _Float16* __restrict__ Ah, const _Float16* __restrict__ Bt,
                 const float* __restrict__ lb0, const float* __restrict__ ub0,
                 float* __restrict__ lacc, float* __restrict__ uacc) {
    __shared__ _Float16 sA[128][32];
    __shared__ _Float16 sB[128][32];

    const int t = threadIdx.x;
    const int lane = t & 63;
    const int w = t >> 6;
    const int waveRow = w >> 1, waveCol = w & 1;
    const int quad = lane >> 4, l15 = lane & 15;

    const int bRow = (blockIdx.x >> 5) * 128;   // output rows j (W2 rows)
    const int bCol = (blockIdx.x & 31) * 128;   // output cols n (W1 cols)

    // staging: each wave issues 4 loads/k-tile: A rows [w*32,w*32+32), B cols same.
    // lane -> row_off = lane>>2 (16 rows/issue), global k-chunk = (lane&3)^((lane>>3)&3)
    const int rIss = lane >> 2;
    const int cSwz = (lane & 3) ^ ((lane >> 3) & 3);
    const _Float16* gA = Ah + (size_t)(bRow + w * 32 + rIss) * NN + cSwz * 8;
    const _Float16* gB = Bt + (size_t)(bCol + w * 32 + rIss) * NN + cSwz * 8;

    f32x4 acc[4][4];
#pragma unroll
    for (int i = 0; i < 4; ++i)
#pragma unroll
        for (int j = 0; j < 4; ++j) acc[i][j] = (f32x4){0.f, 0.f, 0.f, 0.f};

    // frag-read slot xor term: r = waveRow*64 + fr*16 + l15 -> ((r>>1)&3) = ((l15>>1)&3)
    const int fswz = (l15 >> 1) & 3;

    for (int kt = 0; kt < NN / 32; ++kt) {
        const int k0 = kt * 32;
        __syncthreads();   // previous tile's frag reads complete
        async_ld16(&sA[w * 32][0],      gA + k0);
        async_ld16(&sA[w * 32 + 16][0], gA + (size_t)16 * NN + k0);
        async_ld16(&sB[w * 32][0],      gB + k0);
        async_ld16(&sB[w * 32 + 16][0], gB + (size_t)16 * NN + k0);
        __syncthreads();   // vmcnt(0) drained before barrier -> LDS valid

        f16x8 af[4];
#pragma unroll
        for (int fr = 0; fr < 4; ++fr) {
            const int r = waveRow * 64 + fr * 16 + l15;
            af[fr] = *(const f16x8*)&sA[r][(quad ^ fswz) * 8];
        }
#pragma unroll
        for (int fc = 0; fc < 4; ++fc) {
            const int c = waveCol * 64 + fc * 16 + l15;
            const f16x8 bf = *(const f16x8*)&sB[c][(quad ^ fswz) * 8];
#pragma unroll
            for (int fr = 0; fr < 4; ++fr)
                acc[fr][fc] = __builtin_amdgcn_mfma_f32_16x16x32_f16(af[fr], bf, acc[fr][fc], 0, 0, 0);
        }
    }

    // ---- fused epilogue: weighted row-reduction over this block's 128 cols ----
    float lbv[4], ubv[4];
#pragma unroll
    for (int fc = 0; fc < 4; ++fc) {
        const int col = bCol + waveCol * 64 + fc * 16 + l15;
        lbv[fc] = lb0[col];
        ubv[fc] = ub0[col];
    }
#pragma unroll
    for (int fr = 0; fr < 4; ++fr) {
#pragma unroll
        for (int r = 0; r < 4; ++r) {
            float ls = 0.f, us = 0.f;
#pragma unroll
            for (int fc = 0; fc < 4; ++fc) {
                const float m = acc[fr][fc][r];
                const float a = lbv[fc] * m, b = ubv[fc] * m;
                ls += fminf(a, b);
                us += fmaxf(a, b);
            }
            // C/D layout: col = lane&15, row = quad*4 + r (m89/m91)
#pragma unroll
            for (int mk = 1; mk < 16; mk <<= 1) {
                ls += __shfl_xor(ls, mk, 64);
                us += __shfl_xor(us, mk, 64);
            }
            if (l15 == 0) {
                const int row = bRow + waveRow * 64 + fr * 16 + quad * 4 + r;
                atomicAdd(&lacc[row], ls);
                atomicAdd(&uacc[row], us);
            }
        }
    }
}

// W2 fp32 -> Ah fp16 (row-major), fused with cint[j] = b1 . W2[j,:] + b2[j]
__global__ __launch_bounds__(256)
void convertA(const float* __restrict__ W2, const float* __restrict__ b1,
              const float* __restrict__ b2, _Float16* __restrict__ Ah,
              float* __restrict__ cint) {
    const int j = blockIdx.x;
    const int t = threadIdx.x;
    const float* row = W2 + (size_t)j * NN;
    _Float16* orow = Ah + (size_t)j * NN;
    float dot = 0.f;
#pragma unroll
    for (int p = 0; p < 4; ++p) {
        const int i = t * 4 + p * 1024;
        const float4 v = *(const float4*)&row[i];
        const float4 bv = *(const float4*)&b1[i];
        dot += v.x * bv.x + v.y * bv.y + v.z * bv.z + v.w * bv.w;
        f16x4 h;
        h[0] = (_Float16)v.x; h[1] = (_Float16)v.y;
        h[2] = (_Float16)v.z; h[3] = (_Float16)v.w;
        *(f16x4*)&orow[i] = h;
    }
#pragma unroll
    for (int mk = 1; mk < 64; mk <<= 1) dot += __shfl_xor(dot, mk, 64);
    __shared__ float ws4[4];
    if ((t & 63) == 0) ws4[t >> 6] = dot;
    __syncthreads();
    if (t == 0) cint[j] = ws4[0] + ws4[1] + ws4[2] + ws4[3] + b2[j];
}

// W1 fp32 -> Bt fp16 transposed: Bt[n][k] = W1[k][n]; 64x64 LDS tiles
__global__ __launch_bounds__(256)
void convertB(const float* __restrict__ W1, _Float16* __restrict__ Bt) {
    __shared__ float sT[64][65];
    const int bk = (blockIdx.x & 63) * 64;   // W1 row range (contraction k)
    const int bn = (blockIdx.x >> 6) * 64;   // W1 col range (n)
    const int t = threadIdx.x;
    const int r = t >> 4, c4 = (t & 15) * 4;
#pragma unroll
    for (int p = 0; p < 4; ++p) {
        const float4 v = *(const float4*)&W1[(size_t)(bk + r + p * 16) * NN + bn + c4];
        sT[r + p * 16][c4 + 0] = v.x;
        sT[r + p * 16][c4 + 1] = v.y;
        sT[r + p * 16][c4 + 2] = v.z;
        sT[r + p * 16][c4 + 3] = v.w;
    }
    __syncthreads();
    const int n = t >> 4, k4 = (t & 15) * 4;
#pragma unroll
    for (int p = 0; p < 4; ++p) {
        const int nn_ = n + p * 16;
        f16x4 h;
        h[0] = (_Float16)sT[k4 + 0][nn_];
        h[1] = (_Float16)sT[k4 + 1][nn_];
        h[2] = (_Float16)sT[k4 + 2][nn_];
        h[3] = (_Float16)sT[k4 + 3][nn_];
        *(f16x4*)&Bt[(size_t)(bn + nn_) * NN + bk + k4] = h;
    }
}

// zero the full output buffer (float4 streaming stores)
__global__ __launch_bounds__(256)
void clear_out(float4* __restrict__ out, size_t n4) {
    const size_t stride = (size_t)gridDim.x * 256;
    for (size_t p = (size_t)blockIdx.x * 256 + threadIdx.x; p < n4; p += stride)
        out[p] = make_float4(0.f, 0.f, 0.f, 0.f);
}

// DeepPoly LeakyReLU relaxation + diagonal/intercept writes
__global__ __launch_bounds__(256)
void final_kernel(const float* __restrict__ lacc, const float* __restrict__ uacc,
                  const float* __restrict__ cint, const float* __restrict__ ra,
                  float* __restrict__ out) {
    const int j = blockIdx.x * 256 + threadIdx.x;
    if (j >= NN) return;
    const float lb = lacc[j] + cint[j];
    const float ub = uacc[j] + cint[j];
    const float alpha = 1.f / (1.f + expf(-ra[j]));
    float s = (ub - lb * NEG_SLOPE) / (ub - lb);
    if (!(s == s)) s = 0.f;  // NaN -> 0 (ref semantics)
    const float inter = (1.f - s) * ub;
    const bool below = (ub <= 0.f);
    const bool above = (lb >= 0.f);
    const bool crossing = !(below || above);
    const float uslope = crossing ? s : (below ? NEG_SLOPE : 1.f);
    const float uinter = crossing ? inter : 0.f;
    const float v1 = below ? NEG_SLOPE : 1.f;
    const float v2 = crossing ? NEG_SLOPE : (below ? NEG_SLOPE : 1.f);
    const float lslope = alpha * v1 + (1.f - alpha) * v2;

    const size_t N2 = (size_t)NN * NN;
    out[(size_t)j * NN + j] = lslope;             // diag(lslope)
    out[N2 + NN + (size_t)j * NN + j] = uslope;   // diag(uslope)
    out[2 * N2 + NN + j] = uinter;                // uintercept
}

extern "C" void kernel_launch(void* const* d_in, const int* in_sizes, int n_in,
                              void* d_out, int out_size, void* d_ws, size_t ws_size,
                              hipStream_t stream) {
    const float* lb0 = (const float*)d_in[0];
    const float* ub0 = (const float*)d_in[1];
    const float* W1  = (const float*)d_in[2];
    const float* b1  = (const float*)d_in[3];
    const float* W2  = (const float*)d_in[4];
    const float* b2  = (const float*)d_in[5];
    const float* ra  = (const float*)d_in[6];
    float* out = (float*)d_out;

    // d_out doubles as weight scratch (64 MB of its 134 MB) until clear_out
    _Float16* Ahalf = (_Float16*)d_out;
    _Float16* Bt    = Ahalf + (size_t)NN * NN;

    float* lacc = (float*)d_ws;          // [N]
    float* uacc = lacc + NN;             // [N]
    float* cint = uacc + NN;             // [N]

    hipMemsetAsync(d_ws, 0, 2 * NN * sizeof(float), stream);
    convertA<<<dim3(NN), dim3(256), 0, stream>>>(W2, b1, b2, Ahalf, cint);
    convertB<<<dim3(4096), dim3(256), 0, stream>>>(W1, Bt);
    gemm_bounds<<<dim3(1024), dim3(256), 0, stream>>>(Ahalf, Bt, lb0, ub0, lacc, uacc);
    clear_out<<<dim3(4096), dim3(256), 0, stream>>>((float4*)d_out, ((size_t)out_size) / 4);
    final_kernel<<<dim3(NN / 256), dim3(256), 0, stream>>>(lacc, uacc, cint, ra, out);
}

// Round 3
// 398.255 us; speedup vs baseline: 1.8258x; 1.0459x over previous
//
#include <hip/hip_runtime.h>
#include <stdint.h>

#define NN 4096
#define NEG_SLOPE 0.01f

typedef _Float16 f16x8 __attribute__((ext_vector_type(8)));
typedef _Float16 f16x4 __attribute__((ext_vector_type(4)));
typedef float f32x4 __attribute__((ext_vector_type(4)));

// async global->LDS: per-lane global addr, LDS dest = wave-uniform base + lane*16
__device__ __forceinline__ void async_ld16(void* lds, const void* g) {
    __builtin_amdgcn_global_load_lds(
        (__attribute__((address_space(1))) const void*)(const void*)g,
        (__attribute__((address_space(3))) void*)lds, 16, 0, 0);
}

// ---------------------------------------------------------------------------
// GEMM M = W2 @ W1 (fp16) with row-abs-sum epilogue:
//   S[j] += sum_k e[k] * |M[j,k]|,  e = (ub0-lb0)/2
// A = Ah[4096][4096] fp16 (W2 row-major); B = Bt[n][k] fp16 (W1 transposed).
// LDS rows are 128 B (64 fp16) = bank-aligned; 16-B unit w of row r lives at
// slot w ^ (r&7) (fetch-side permutation: global_load_lds lane λ of an 8-row
// issue fetches row λ>>3, unit (λ&7)^(λ>>3)).  Frag ds_read_b128 then lands
// 8 lanes per 16-B unit = 8 accesses/bank = the structural LDS minimum.
// ---------------------------------------------------------------------------
__global__ __launch_bounds__(256, 4)
void gemm_S(const _Float16* __restrict__ Ah, const _Float16* __restrict__ Bt,
            const float* __restrict__ lb0, const float* __restrict__ ub0,
            float* __restrict__ S) {
    __shared__ _Float16 sA[128][64];   // 16 KB
    __shared__ _Float16 sB[128][64];   // 16 KB
    const int t = threadIdx.x;
    const int lane = t & 63;
    const int w = t >> 6;
    const int waveRow = w >> 1, waveCol = w & 1;
    const int quad = lane >> 4, l15 = lane & 15, l7 = lane & 7;

    const int bRow = (blockIdx.x >> 5) * 128;   // output rows j
    const int bCol = (blockIdx.x & 31) * 128;   // output cols n

    // staging: wave w stages A rows [w*32, w*32+32) + B rows same; 4 issues each
    const int rOff = lane >> 3;                 // 8 rows per issue
    const int uG   = (lane & 7) ^ (lane >> 3);  // fetch-side XOR permutation
    const _Float16* gA = Ah + (size_t)(bRow + w * 32 + rOff) * NN + uG * 8;
    const _Float16* gB = Bt + (size_t)(bCol + w * 32 + rOff) * NN + uG * 8;

    f32x4 acc[4][4];
#pragma unroll
    for (int i = 0; i < 4; ++i)
#pragma unroll
        for (int j = 0; j < 4; ++j) acc[i][j] = (f32x4){0.f, 0.f, 0.f, 0.f};

    for (int kt = 0; kt < NN / 64; ++kt) {
        const int k0 = kt * 64;
        __syncthreads();   // previous tile's frag reads complete
#pragma unroll
        for (int i = 0; i < 4; ++i) {
            async_ld16(&sA[w * 32 + i * 8][0], gA + (size_t)(i * 8) * NN + k0);
            async_ld16(&sB[w * 32 + i * 8][0], gB + (size_t)(i * 8) * NN + k0);
        }
        __syncthreads();   // vmcnt(0) drained at barrier -> LDS valid

#pragma unroll
        for (int s = 0; s < 2; ++s) {
            f16x8 af[4];
#pragma unroll
            for (int fr = 0; fr < 4; ++fr) {
                const int r = waveRow * 64 + fr * 16 + l15;   // r&7 == l7
                af[fr] = *(const f16x8*)&sA[r][((s * 4 + quad) ^ l7) * 8];
            }
#pragma unroll
            for (int fc = 0; fc < 4; ++fc) {
                const int c = waveCol * 64 + fc * 16 + l15;
                const f16x8 bf = *(const f16x8*)&sB[c][((s * 4 + quad) ^ l7) * 8];
#pragma unroll
                for (int fr = 0; fr < 4; ++fr)
                    acc[fr][fc] = __builtin_amdgcn_mfma_f32_16x16x32_f16(af[fr], bf, acc[fr][fc], 0, 0, 0);
            }
        }
    }

    // epilogue: S[row] += sum over this block's 128 cols of e[col]*|m|
    float ev[4];
#pragma unroll
    for (int fc = 0; fc < 4; ++fc) {
        const int col = bCol + waveCol * 64 + fc * 16 + l15;
        ev[fc] = 0.5f * (ub0[col] - lb0[col]);
    }
#pragma unroll
    for (int fr = 0; fr < 4; ++fr) {
#pragma unroll
        for (int r = 0; r < 4; ++r) {
            float sv = 0.f;
#pragma unroll
            for (int fc = 0; fc < 4; ++fc)
                sv += ev[fc] * fabsf(acc[fr][fc][r]);
            // C/D layout: col = lane&15, row = quad*4 + r (m89/m91)
#pragma unroll
            for (int mk = 1; mk < 16; mk <<= 1)
                sv += __shfl_xor(sv, mk, 64);
            if (l15 == 0) {
                const int row = bRow + waveRow * 64 + fr * 16 + quad * 4 + r;
                atomicAdd(&S[row], sv);
            }
        }
    }
}

// W1 fp32 -> Bt fp16 transposed (Bt[n][i] = W1[i][n]) fused with v = W1 @ c,
// c = (lb0+ub0)/2.  v accumulated via per-row atomics (v pre-zeroed by memset).
__global__ __launch_bounds__(256)
void prepB(const float* __restrict__ W1, const float* __restrict__ lb0,
           const float* __restrict__ ub0, _Float16* __restrict__ Bt,
           float* __restrict__ v) {
    __shared__ float sT[64][65];
    const int bi = (blockIdx.x & 63) * 64;   // W1 row range (i)
    const int bn = (blockIdx.x >> 6) * 64;   // W1 col range (n)
    const int t = threadIdx.x;
    const int r = t >> 4, c4 = (t & 15) * 4;

    const float4 lv = *(const float4*)&lb0[bn + c4];
    const float4 uv = *(const float4*)&ub0[bn + c4];
    const float cw0 = 0.5f * (lv.x + uv.x), cw1 = 0.5f * (lv.y + uv.y);
    const float cw2 = 0.5f * (lv.z + uv.z), cw3 = 0.5f * (lv.w + uv.w);

#pragma unroll
    for (int p = 0; p < 4; ++p) {
        const float4 a = *(const float4*)&W1[(size_t)(bi + r + p * 16) * NN + bn + c4];
        sT[r + p * 16][c4 + 0] = a.x;
        sT[r + p * 16][c4 + 1] = a.y;
        sT[r + p * 16][c4 + 2] = a.z;
        sT[r + p * 16][c4 + 3] = a.w;
        float part = a.x * cw0 + a.y * cw1 + a.z * cw2 + a.w * cw3;
#pragma unroll
        for (int mk = 1; mk < 16; mk <<= 1)
            part += __shfl_xor(part, mk, 64);
        if ((t & 15) == 0) atomicAdd(&v[bi + r + p * 16], part);
    }
    __syncthreads();
    const int n = t >> 4, k4 = (t & 15) * 4;
#pragma unroll
    for (int p = 0; p < 4; ++p) {
        const int nn_ = n + p * 16;
        f16x4 h;
        h[0] = (_Float16)sT[k4 + 0][nn_];
        h[1] = (_Float16)sT[k4 + 1][nn_];
        h[2] = (_Float16)sT[k4 + 2][nn_];
        h[3] = (_Float16)sT[k4 + 3][nn_];
        *(f16x4*)&Bt[(size_t)(bn + nn_) * NN + bi + k4] = h;
    }
}

// W2 fp32 -> Ah fp16 (row-major) fused with u[j] = W2[j,:].v,
// cj[j] = W2[j,:].b1 + b2[j], and S[j] = 0 (pre-GEMM init).
__global__ __launch_bounds__(256)
void prepA(const float* __restrict__ W2, const float* __restrict__ b1,
           const float* __restrict__ b2, const float* __restrict__ v,
           _Float16* __restrict__ Ah, float* __restrict__ u,
           float* __restrict__ cj, float* __restrict__ S) {
    const int j = blockIdx.x;
    const int t = threadIdx.x;
    const float* row = W2 + (size_t)j * NN;
    _Float16* orow = Ah + (size_t)j * NN;
    float d1 = 0.f, d2 = 0.f;
#pragma unroll
    for (int p = 0; p < 4; ++p) {
        const int i = t * 4 + p * 1024;
        const float4 a = *(const float4*)&row[i];
        const float4 bb = *(const float4*)&b1[i];
        const float4 vv = *(const float4*)&v[i];
        d1 += a.x * bb.x + a.y * bb.y + a.z * bb.z + a.w * bb.w;
        d2 += a.x * vv.x + a.y * vv.y + a.z * vv.z + a.w * vv.w;
        f16x4 h;
        h[0] = (_Float16)a.x; h[1] = (_Float16)a.y;
        h[2] = (_Float16)a.z; h[3] = (_Float16)a.w;
        *(f16x4*)&orow[i] = h;
    }
#pragma unroll
    for (int mk = 1; mk < 64; mk <<= 1) {
        d1 += __shfl_xor(d1, mk, 64);
        d2 += __shfl_xor(d2, mk, 64);
    }
    __shared__ float w1s[4], w2s[4];
    if ((t & 63) == 0) { w1s[t >> 6] = d1; w2s[t >> 6] = d2; }
    __syncthreads();
    if (t == 0) {
        cj[j] = w1s[0] + w1s[1] + w1s[2] + w1s[3] + b2[j];
        u[j]  = w2s[0] + w2s[1] + w2s[2] + w2s[3];
        S[j]  = 0.f;
    }
}

// Fused clear + output write: one pass over all 134 MB of d_out.
// blocks 0..4095: diag(lslope) rows; 4096..8191: diag(uslope) rows;
// 8192: lintercept (zeros); 8193: uintercept.
__global__ __launch_bounds__(256)
void write_out(const float* __restrict__ S, const float* __restrict__ u,
               const float* __restrict__ cj, const float* __restrict__ ra,
               float* __restrict__ out) {
    const size_t N2 = (size_t)NN * NN;
    const int b = blockIdx.x;
    const int t = threadIdx.x;
    if (b < 8192) {
        const int j = b & 4095;
        const bool isU = b >= 4096;
        const float base = u[j] + cj[j];
        const float Sv = S[j];
        const float lb = base - Sv, ub = base + Sv;
        const float alpha = 1.f / (1.f + expf(-ra[j]));
        float s = (ub - lb * NEG_SLOPE) / (ub - lb);
        if (!(s == s)) s = 0.f;
        const bool below = (ub <= 0.f), above = (lb >= 0.f);
        const bool crossing = !(below || above);
        const float uslope = crossing ? s : (below ? NEG_SLOPE : 1.f);
        const float v1 = below ? NEG_SLOPE : 1.f;
        const float v2 = crossing ? NEG_SLOPE : v1;
        const float lslope = alpha * v1 + (1.f - alpha) * v2;
        const float dval = isU ? uslope : lslope;
        float4* rowp = (float4*)(out + (isU ? (N2 + NN) : (size_t)0) + (size_t)j * NN);
        const int dq = j >> 2, dr = j & 3;
#pragma unroll
        for (int q = 0; q < 4; ++q) {
            const int i4 = t + q * 256;
            float4 z = make_float4(0.f, 0.f, 0.f, 0.f);
            if (i4 == dq) ((float*)&z)[dr] = dval;
            rowp[i4] = z;
        }
    } else if (b == 8192) {
        float4* rowp = (float4*)(out + N2);
#pragma unroll
        for (int q = 0; q < 4; ++q)
            rowp[t + q * 256] = make_float4(0.f, 0.f, 0.f, 0.f);
    } else {
        float* rowp = out + 2 * N2 + NN;
#pragma unroll
        for (int q = 0; q < 16; ++q) {
            const int j = t + q * 256;
            const float base = u[j] + cj[j];
            const float Sv = S[j];
            const float lb = base - Sv, ub = base + Sv;
            float s = (ub - lb * NEG_SLOPE) / (ub - lb);
            if (!(s == s)) s = 0.f;
            const bool below = (ub <= 0.f), above = (lb >= 0.f);
            const bool crossing = !(below || above);
            rowp[j] = crossing ? (1.f - s) * ub : 0.f;
        }
    }
}

extern "C" void kernel_launch(void* const* d_in, const int* in_sizes, int n_in,
                              void* d_out, int out_size, void* d_ws, size_t ws_size,
                              hipStream_t stream) {
    const float* lb0 = (const float*)d_in[0];
    const float* ub0 = (const float*)d_in[1];
    const float* W1  = (const float*)d_in[2];
    const float* b1  = (const float*)d_in[3];
    const float* W2  = (const float*)d_in[4];
    const float* b2  = (const float*)d_in[5];
    const float* ra  = (const float*)d_in[6];
    float* out = (float*)d_out;

    // d_out doubles as fp16 weight scratch (first 64 MB) until write_out
    _Float16* Ahalf = (_Float16*)d_out;
    _Float16* Bt    = Ahalf + (size_t)NN * NN;

    float* v  = (float*)d_ws;   // [N]  (atomic-accumulated; needs zeroing)
    float* S  = v + NN;         // [N]  (zeroed by prepA)
    float* u  = S + NN;         // [N]
    float* cj = u + NN;         // [N]

    hipMemsetAsync(v, 0, NN * sizeof(float), stream);
    prepB<<<dim3(4096), dim3(256), 0, stream>>>(W1, lb0, ub0, Bt, v);
    prepA<<<dim3(NN), dim3(256), 0, stream>>>(W2, b1, b2, v, Ahalf, u, cj, S);
    gemm_S<<<dim3(1024), dim3(256), 0, stream>>>(Ahalf, Bt, lb0, ub0, S);
    write_out<<<dim3(8194), dim3(256), 0, stream>>>(S, u, cj, ra, out);
}

// Round 5
// 379.177 us; speedup vs baseline: 1.9176x; 1.0503x over previous
//
#include <hip/hip_runtime.h>
#include <stdint.h>

#define NN 4096
#define NEG_SLOPE 0.01f

typedef _Float16 f16x8 __attribute__((ext_vector_type(8)));
typedef _Float16 f16x4 __attribute__((ext_vector_type(4)));
typedef float f32x4 __attribute__((ext_vector_type(4)));

// float indices into out: [lslope diag NxN][lintercept N][uslope diag NxN][uintercept N]
#define L_DIAG 0
#define L_INT  16777216
#define U_DIAG 16781312
#define U_INT  33558528
#define TAIL0  33554432   // gemm zeroes floats [L_INT, TAIL0)

// async global->LDS: per-lane global addr, LDS dest = wave-uniform base + lane*16
__device__ __forceinline__ void async_ld16(void* lds, const void* g) {
    __builtin_amdgcn_global_load_lds(
        (__attribute__((address_space(1))) const void*)(const void*)g,
        (__attribute__((address_space(3))) void*)lds, 16, 0, 0);
}

// ---------------------------------------------------------------------------
// GEMM M = W2 @ W1 (fp16) with dual row-reduction epilogue:
//   S[j] += sum_n e[n]*|M[j,n]|,  U[j] += sum_n c[n]*M[j,n]
//   e = (ub0-lb0)/2, c = (ub0+lb0)/2
// Plus interleaved zero-fill of d_out floats [L_INT, TAIL0) (64 MB) on the
// otherwise-idle store pipe: 1 nontemporal f32x4 store / thread / 4 k-iters.
// LDS: 128-B rows, fetch-side XOR permutation -> conflict-free ds_read_b128
// (verified: SQ_LDS_BANK_CONFLICT = 0 in R2/R3).
// ---------------------------------------------------------------------------
__global__ __launch_bounds__(256, 4)
void gemm_SU(const _Float16* __restrict__ Ah, const _Float16* __restrict__ Bt,
             const float* __restrict__ lb0, const float* __restrict__ ub0,
             float* __restrict__ S, float* __restrict__ U,
             f32x4* __restrict__ zbase) {
    __shared__ _Float16 sA[128][64];   // 16 KB
    __shared__ _Float16 sB[128][64];   // 16 KB
    const int t = threadIdx.x;
    const int lane = t & 63;
    const int w = t >> 6;
    const int waveRow = w >> 1, waveCol = w & 1;
    const int quad = lane >> 4, l15 = lane & 15, l7 = lane & 7;

    const int bRow = (blockIdx.x >> 5) * 128;   // output rows j
    const int bCol = (blockIdx.x & 31) * 128;   // output cols n

    const int rOff = lane >> 3;                 // 8 rows per issue
    const int uG   = (lane & 7) ^ (lane >> 3);  // fetch-side XOR permutation
    const _Float16* gA = Ah + (size_t)(bRow + w * 32 + rOff) * NN + uG * 8;
    const _Float16* gB = Bt + (size_t)(bCol + w * 32 + rOff) * NN + uG * 8;

    f32x4 acc[4][4];
#pragma unroll
    for (int i = 0; i < 4; ++i)
#pragma unroll
        for (int j = 0; j < 4; ++j) acc[i][j] = (f32x4){0.f, 0.f, 0.f, 0.f};

    const f32x4 zv = (f32x4){0.f, 0.f, 0.f, 0.f};

    for (int kt = 0; kt < NN / 64; ++kt) {
        const int k0 = kt * 64;
        __syncthreads();   // previous tile's frag reads complete
#pragma unroll
        for (int i = 0; i < 4; ++i) {
            async_ld16(&sA[w * 32 + i * 8][0], gA + (size_t)(i * 8) * NN + k0);
            async_ld16(&sB[w * 32 + i * 8][0], gB + (size_t)(i * 8) * NN + k0);
        }
        __syncthreads();   // vmcnt(0) drained at barrier -> LDS valid

#pragma unroll
        for (int s = 0; s < 2; ++s) {
            f16x8 af[4];
#pragma unroll
            for (int fr = 0; fr < 4; ++fr) {
                const int r = waveRow * 64 + fr * 16 + l15;   // r&7 == l7
                af[fr] = *(const f16x8*)&sA[r][((s * 4 + quad) ^ l7) * 8];
            }
#pragma unroll
            for (int fc = 0; fc < 4; ++fc) {
                const int c = waveCol * 64 + fc * 16 + l15;
                const f16x8 bf = *(const f16x8*)&sB[c][((s * 4 + quad) ^ l7) * 8];
#pragma unroll
                for (int fr = 0; fr < 4; ++fr)
                    acc[fr][fc] = __builtin_amdgcn_mfma_f32_16x16x32_f16(af[fr], bf, acc[fr][fc], 0, 0, 0);
            }
        }

        // interleaved zero-fill: hides d_out clearing under MFMA
        if ((kt & 3) == 0) {
            const int zi = kt >> 2;   // 0..15
            __builtin_nontemporal_store(zv,
                zbase + (size_t)blockIdx.x * 4096 + zi * 256 + t);
        }
    }

    // epilogue: dual weighted row-reduction over this block's 128 cols
    float ev[4], cv[4];
#pragma unroll
    for (int fc = 0; fc < 4; ++fc) {
        const int col = bCol + waveCol * 64 + fc * 16 + l15;
        const float l = lb0[col], u_ = ub0[col];
        ev[fc] = 0.5f * (u_ - l);
        cv[fc] = 0.5f * (u_ + l);
    }
#pragma unroll
    for (int fr = 0; fr < 4; ++fr) {
#pragma unroll
        for (int r = 0; r < 4; ++r) {
            float sv = 0.f, uv = 0.f;
#pragma unroll
            for (int fc = 0; fc < 4; ++fc) {
                const float m = acc[fr][fc][r];
                sv += ev[fc] * fabsf(m);
                uv += cv[fc] * m;
            }
            // C/D layout: col = lane&15, row = quad*4 + r (m89/m91)
#pragma unroll
            for (int mk = 1; mk < 16; mk <<= 1) {
                sv += __shfl_xor(sv, mk, 64);
                uv += __shfl_xor(uv, mk, 64);
            }
            if (l15 == 0) {
                const int row = bRow + waveRow * 64 + fr * 16 + quad * 4 + r;
                atomicAdd(&S[row], sv);
                atomicAdd(&U[row], uv);
            }
        }
    }
}

// ---------------------------------------------------------------------------
// One prep kernel, 8192 blocks:
//  blocks 0..4095:  W2 row j -> Ah fp16; cj[j] = W2[j,:].b1 + b2[j]; S[j]=U[j]=0
//  blocks 4096..8191: 64x64 transpose tile of W1 -> Bt fp16 (Bt[n][k]=W1[k][n])
// ---------------------------------------------------------------------------
__global__ __launch_bounds__(256)
void prep(const float* __restrict__ W2, const float* __restrict__ W1,
          const float* __restrict__ b1, const float* __restrict__ b2,
          _Float16* __restrict__ Ah, _Float16* __restrict__ Bt,
          float* __restrict__ cj, float* __restrict__ S, float* __restrict__ U) {
    __shared__ float sT[64][65];
    __shared__ float w4[4];
    const int b = blockIdx.x;
    const int t = threadIdx.x;
    if (b < 4096) {
        const int j = b;
        const float* row = W2 + (size_t)j * NN;
        _Float16* orow = Ah + (size_t)j * NN;
        float d1 = 0.f;
#pragma unroll
        for (int p = 0; p < 4; ++p) {
            const int i = p * 1024 + t * 4;
            const float4 a = *(const float4*)&row[i];
            const float4 bb = *(const float4*)&b1[i];
            d1 += a.x * bb.x + a.y * bb.y + a.z * bb.z + a.w * bb.w;
            f16x4 h;
            h[0] = (_Float16)a.x; h[1] = (_Float16)a.y;
            h[2] = (_Float16)a.z; h[3] = (_Float16)a.w;
            *(f16x4*)&orow[i] = h;
        }
#pragma unroll
        for (int mk = 1; mk < 64; mk <<= 1) d1 += __shfl_xor(d1, mk, 64);
        if ((t & 63) == 0) w4[t >> 6] = d1;
        __syncthreads();
        if (t == 0) {
            cj[j] = w4[0] + w4[1] + w4[2] + w4[3] + b2[j];
            S[j] = 0.f;
            U[j] = 0.f;
        }
    } else {
        const int tile = b - 4096;
        const int bi = (tile & 63) * 64;   // W1 row range (contraction k)
        const int bn = (tile >> 6) * 64;   // W1 col range (n)
        const int r = t >> 4, c4 = (t & 15) * 4;
#pragma unroll
        for (int p = 0; p < 4; ++p) {
            const float4 a = *(const float4*)&W1[(size_t)(bi + r + p * 16) * NN + bn + c4];
            sT[r + p * 16][c4 + 0] = a.x;
            sT[r + p * 16][c4 + 1] = a.y;
            sT[r + p * 16][c4 + 2] = a.z;
            sT[r + p * 16][c4 + 3] = a.w;
        }
        __syncthreads();
        const int n = t >> 4, k4 = (t & 15) * 4;
#pragma unroll
        for (int p = 0; p < 4; ++p) {
            const int nn_ = n + p * 16;
            f16x4 h;
            h[0] = (_Float16)sT[k4 + 0][nn_];
            h[1] = (_Float16)sT[k4 + 1][nn_];
            h[2] = (_Float16)sT[k4 + 2][nn_];
            h[3] = (_Float16)sT[k4 + 3][nn_];
            *(f16x4*)&Bt[(size_t)(bn + nn_) * NN + bi + k4] = h;
        }
    }
}

// ---- DeepPoly relaxation helpers ----
__device__ __forceinline__ void get_lub(int j, const float* S, const float* U,
                                        const float* cj, float& lb, float& ub) {
    const float base = U[j] + cj[j], Sv = S[j];
    lb = base - Sv;
    ub = base + Sv;
}
__device__ __forceinline__ float slope_of(float lb, float ub) {
    float s = (ub - lb * NEG_SLOPE) / (ub - lb);
    if (!(s == s)) s = 0.f;
    return s;
}
__device__ __forceinline__ float uslope_of(float lb, float ub) {
    const bool below = (ub <= 0.f), above = (lb >= 0.f);
    return (!(below || above)) ? slope_of(lb, ub) : (below ? NEG_SLOPE : 1.f);
}

// ---------------------------------------------------------------------------
// finish, grid 4114:
//  blocks 0..4095:  clear lslope row j (scratch region) + write diag value
//  blocks 4096..4111: scattered uslope diag writes (j<4095; region gemm-zeroed)
//  block 4112: zero tail floats [TAIL0, U_INT) (last uslope row) incl. diag 4095
//  block 4113: uintercept row
// ---------------------------------------------------------------------------
__global__ __launch_bounds__(256)
void finish(const float* __restrict__ S, const float* __restrict__ U,
            const float* __restrict__ cj, const float* __restrict__ ra,
            float* __restrict__ out) {
    const int b = blockIdx.x;
    const int t = threadIdx.x;
    if (b < 4096) {
        const int j = b;
        float lb, ub;
        get_lub(j, S, U, cj, lb, ub);
        const float alpha = 1.f / (1.f + expf(-ra[j]));
        const bool below = (ub <= 0.f), above = (lb >= 0.f);
        const bool crossing = !(below || above);
        const float v1 = below ? NEG_SLOPE : 1.f;
        const float v2 = crossing ? NEG_SLOPE : v1;
        const float lslope = alpha * v1 + (1.f - alpha) * v2;
        f32x4* rowp = (f32x4*)(out + (size_t)j * NN);
        const int dq = j >> 2, dr = j & 3;
#pragma unroll
        for (int q = 0; q < 4; ++q) {
            const int i4 = t + q * 256;
            f32x4 z = (f32x4){0.f, 0.f, 0.f, 0.f};
            if (i4 == dq) z[dr] = lslope;
            __builtin_nontemporal_store(z, &rowp[i4]);
        }
    } else if (b < 4112) {
        const int j = (b - 4096) * 256 + t;
        if (j < 4095) {   // j==4095 lives in the tail block's region
            float lb, ub;
            get_lub(j, S, U, cj, lb, ub);
            out[U_DIAG + (size_t)j * NN + j] = uslope_of(lb, ub);
        }
    } else if (b == 4112) {
        f32x4* p = (f32x4*)(out + TAIL0);
#pragma unroll
        for (int q = 0; q < 4; ++q) {
            const int i4 = t + q * 256;
            f32x4 z = (f32x4){0.f, 0.f, 0.f, 0.f};
            if (i4 == 1023) {
                float lb, ub;
                get_lub(4095, S, U, cj, lb, ub);
                z[3] = uslope_of(lb, ub);
            }
            __builtin_nontemporal_store(z, &p[i4]);
        }
    } else {
#pragma unroll
        for (int q = 0; q < 16; ++q) {
            const int j = t + q * 256;
            float lb, ub;
            get_lub(j, S, U, cj, lb, ub);
            const bool below = (ub <= 0.f), above = (lb >= 0.f);
            const bool crossing = !(below || above);
            out[U_INT + j] = crossing ? (1.f - slope_of(lb, ub)) * ub : 0.f;
        }
    }
}

extern "C" void kernel_launch(void* const* d_in, const int* in_sizes, int n_in,
                              void* d_out, int out_size, void* d_ws, size_t ws_size,
                              hipStream_t stream) {
    const float* lb0 = (const float*)d_in[0];
    const float* ub0 = (const float*)d_in[1];
    const float* W1  = (const float*)d_in[2];
    const float* b1  = (const float*)d_in[3];
    const float* W2  = (const float*)d_in[4];
    const float* b2  = (const float*)d_in[5];
    const float* ra  = (const float*)d_in[6];
    float* out = (float*)d_out;

    // d_out doubles as fp16 weight scratch (first 64 MB) until finish
    _Float16* Ah = (_Float16*)d_out;
    _Float16* Bt = Ah + (size_t)NN * NN;

    float* S  = (float*)d_ws;   // [N] zeroed by prep
    float* U  = S + NN;         // [N] zeroed by prep
    float* cj = U + NN;         // [N]

    prep<<<dim3(8192), dim3(256), 0, stream>>>(W2, W1, b1, b2, Ah, Bt, cj, S, U);
    gemm_SU<<<dim3(1024), dim3(256), 0, stream>>>(Ah, Bt, lb0, ub0, S, U,
                                                  (f32x4*)(out + L_INT));
    finish<<<dim3(4114), dim3(256), 0, stream>>>(S, U, cj, ra, out);
}

// Round 6
// 374.861 us; speedup vs baseline: 1.9397x; 1.0115x over previous
//
#include <hip/hip_runtime.h>
#include <stdint.h>

#define NN 4096
#define NEG_SLOPE 0.01f

typedef _Float16 f16x8 __attribute__((ext_vector_type(8)));
typedef _Float16 f16x4 __attribute__((ext_vector_type(4)));
typedef float f32x4 __attribute__((ext_vector_type(4)));

// float indices into out: [lslope diag NxN][lintercept N][uslope diag NxN][uintercept N]
#define L_INT  16777216
#define U_DIAG 16781312
#define U_INT  33558528
#define TAIL0  33554432   // slow path: gemm zeroes floats [L_INT, TAIL0)
#define TAIL2  33554432   // fast path: gemm zeroes floats [0, TAIL2)

// async global->LDS: per-lane global addr, LDS dest = wave-uniform base + lane*16
__device__ __forceinline__ void async_ld16(void* lds, const void* g) {
    __builtin_amdgcn_global_load_lds(
        (__attribute__((address_space(1))) const void*)(const void*)g,
        (__attribute__((address_space(3))) void*)lds, 16, 0, 0);
}

// ---------------------------------------------------------------------------
// GEMM M = W2 @ W1 (fp16) with dual row-reduction epilogue:
//   S[j] += sum_n e[n]*|M[j,n]|,  U[j] += sum_n c[n]*M[j,n]
// Interleaved zero-fill of (64/EVERY)*256 f32x4 per block of d_out on the
// otherwise-idle store pipe (R5 measured: 64 MB hidden stores cost +3 us).
// LDS: 128-B rows, fetch-side XOR permutation -> SQ_LDS_BANK_CONFLICT == 0.
// ---------------------------------------------------------------------------
template<int EVERY>
__global__ __launch_bounds__(256, 4)
void gemm_SU(const _Float16* __restrict__ Ah, const _Float16* __restrict__ Bt,
             const float* __restrict__ lb0, const float* __restrict__ ub0,
             float* __restrict__ S, float* __restrict__ U,
             f32x4* __restrict__ zbase) {
    __shared__ _Float16 sA[128][64];   // 16 KB
    __shared__ _Float16 sB[128][64];   // 16 KB
    const int t = threadIdx.x;
    const int lane = t & 63;
    const int w = t >> 6;
    const int waveRow = w >> 1, waveCol = w & 1;
    const int quad = lane >> 4, l15 = lane & 15, l7 = lane & 7;

    const int bRow = (blockIdx.x >> 5) * 128;   // output rows j
    const int bCol = (blockIdx.x & 31) * 128;   // output cols n

    const int rOff = lane >> 3;                 // 8 rows per issue
    const int uG   = (lane & 7) ^ (lane >> 3);  // fetch-side XOR permutation
    const _Float16* gA = Ah + (size_t)(bRow + w * 32 + rOff) * NN + uG * 8;
    const _Float16* gB = Bt + (size_t)(bCol + w * 32 + rOff) * NN + uG * 8;

    f32x4 acc[4][4];
#pragma unroll
    for (int i = 0; i < 4; ++i)
#pragma unroll
        for (int j = 0; j < 4; ++j) acc[i][j] = (f32x4){0.f, 0.f, 0.f, 0.f};

    const f32x4 zv = (f32x4){0.f, 0.f, 0.f, 0.f};
    const int NZB = (64 / EVERY) * 256;   // f32x4 per block

    for (int kt = 0; kt < NN / 64; ++kt) {
        const int k0 = kt * 64;
        __syncthreads();   // previous tile's frag reads complete
#pragma unroll
        for (int i = 0; i < 4; ++i) {
            async_ld16(&sA[w * 32 + i * 8][0], gA + (size_t)(i * 8) * NN + k0);
            async_ld16(&sB[w * 32 + i * 8][0], gB + (size_t)(i * 8) * NN + k0);
        }
        __syncthreads();   // vmcnt(0) drained at barrier -> LDS valid

#pragma unroll
        for (int s = 0; s < 2; ++s) {
            f16x8 af[4];
#pragma unroll
            for (int fr = 0; fr < 4; ++fr) {
                const int r = waveRow * 64 + fr * 16 + l15;   // r&7 == l7
                af[fr] = *(const f16x8*)&sA[r][((s * 4 + quad) ^ l7) * 8];
            }
#pragma unroll
            for (int fc = 0; fc < 4; ++fc) {
                const int c = waveCol * 64 + fc * 16 + l15;
                const f16x8 bf = *(const f16x8*)&sB[c][((s * 4 + quad) ^ l7) * 8];
#pragma unroll
                for (int fr = 0; fr < 4; ++fr)
                    acc[fr][fc] = __builtin_amdgcn_mfma_f32_16x16x32_f16(af[fr], bf, acc[fr][fc], 0, 0, 0);
            }
        }

        // interleaved zero-fill of d_out, hidden under MFMA
        if ((kt & (EVERY - 1)) == 0) {
            const int zi = kt / EVERY;
            __builtin_nontemporal_store(zv,
                zbase + (size_t)blockIdx.x * NZB + zi * 256 + t);
        }
    }

    // epilogue: dual weighted row-reduction over this block's 128 cols
    float ev[4], cv[4];
#pragma unroll
    for (int fc = 0; fc < 4; ++fc) {
        const int col = bCol + waveCol * 64 + fc * 16 + l15;
        const float l = lb0[col], u_ = ub0[col];
        ev[fc] = 0.5f * (u_ - l);
        cv[fc] = 0.5f * (u_ + l);
    }
#pragma unroll
    for (int fr = 0; fr < 4; ++fr) {
#pragma unroll
        for (int r = 0; r < 4; ++r) {
            float sv = 0.f, uv = 0.f;
#pragma unroll
            for (int fc = 0; fc < 4; ++fc) {
                const float m = acc[fr][fc][r];
                sv += ev[fc] * fabsf(m);
                uv += cv[fc] * m;
            }
            // C/D layout: col = lane&15, row = quad*4 + r (m89/m91)
#pragma unroll
            for (int mk = 1; mk < 16; mk <<= 1) {
                sv += __shfl_xor(sv, mk, 64);
                uv += __shfl_xor(uv, mk, 64);
            }
            if (l15 == 0) {
                const int row = bRow + waveRow * 64 + fr * 16 + quad * 4 + r;
                atomicAdd(&S[row], sv);
                atomicAdd(&U[row], uv);
            }
        }
    }
}

// ---------------------------------------------------------------------------
// prep, 8192 blocks:
//  blocks 0..4095:  W2 row j -> Ah fp16 (f16x8 stores); cj[j] = W2[j,:].b1+b2[j];
//                   S[j]=U[j]=0
//  blocks 4096..8191: 64x64 transpose tile of W1 -> Bt fp16 (Bt[n][k]=W1[k][n]),
//                   f16x8 stores (16 B/lane)
// ---------------------------------------------------------------------------
__global__ __launch_bounds__(256)
void prep(const float* __restrict__ W2, const float* __restrict__ W1,
          const float* __restrict__ b1, const float* __restrict__ b2,
          _Float16* __restrict__ Ah, _Float16* __restrict__ Bt,
          float* __restrict__ cj, float* __restrict__ S, float* __restrict__ U) {
    __shared__ float sT[64][65];
    __shared__ float w4[4];
    const int b = blockIdx.x;
    const int t = threadIdx.x;
    if (b < 4096) {
        const int j = b;
        const float* row = W2 + (size_t)j * NN;
        _Float16* orow = Ah + (size_t)j * NN;
        float d1 = 0.f;
#pragma unroll
        for (int p = 0; p < 2; ++p) {
            const int i = p * 2048 + t * 8;
            const float4 a0 = *(const float4*)&row[i];
            const float4 a1 = *(const float4*)&row[i + 4];
            const float4 b0 = *(const float4*)&b1[i];
            const float4 b1v = *(const float4*)&b1[i + 4];
            d1 += a0.x * b0.x + a0.y * b0.y + a0.z * b0.z + a0.w * b0.w;
            d1 += a1.x * b1v.x + a1.y * b1v.y + a1.z * b1v.z + a1.w * b1v.w;
            f16x8 h;
            h[0] = (_Float16)a0.x; h[1] = (_Float16)a0.y;
            h[2] = (_Float16)a0.z; h[3] = (_Float16)a0.w;
            h[4] = (_Float16)a1.x; h[5] = (_Float16)a1.y;
            h[6] = (_Float16)a1.z; h[7] = (_Float16)a1.w;
            *(f16x8*)&orow[i] = h;
        }
#pragma unroll
        for (int mk = 1; mk < 64; mk <<= 1) d1 += __shfl_xor(d1, mk, 64);
        if ((t & 63) == 0) w4[t >> 6] = d1;
        __syncthreads();
        if (t == 0) {
            cj[j] = w4[0] + w4[1] + w4[2] + w4[3] + b2[j];
            S[j] = 0.f;
            U[j] = 0.f;
        }
    } else {
        const int tile = b - 4096;
        const int bi = (tile & 63) * 64;   // W1 row range (contraction k)
        const int bn = (tile >> 6) * 64;   // W1 col range (n)
        const int r = t >> 4, c4 = (t & 15) * 4;
#pragma unroll
        for (int p = 0; p < 4; ++p) {
            const float4 a = *(const float4*)&W1[(size_t)(bi + r + p * 16) * NN + bn + c4];
            sT[r + p * 16][c4 + 0] = a.x;
            sT[r + p * 16][c4 + 1] = a.y;
            sT[r + p * 16][c4 + 2] = a.z;
            sT[r + p * 16][c4 + 3] = a.w;
        }
        __syncthreads();
        // write side: lane handles 8 contiguous k (16 B); sT bank stride 65%32=1
        // -> bank = (k + n) & 31, 2-way over the wave = free
        const int k8 = (t & 7) * 8;
#pragma unroll
        for (int p = 0; p < 2; ++p) {
            const int n = (t >> 3) + p * 32;
            f16x8 h;
#pragma unroll
            for (int e = 0; e < 8; ++e) h[e] = (_Float16)sT[k8 + e][n];
            *(f16x8*)&Bt[(size_t)(bn + n) * NN + bi + k8] = h;
        }
    }
}

// ---- DeepPoly relaxation helpers ----
__device__ __forceinline__ void get_lub(int j, const float* S, const float* U,
                                        const float* cj, float& lb, float& ub) {
    const float base = U[j] + cj[j], Sv = S[j];
    lb = base - Sv;
    ub = base + Sv;
}
__device__ __forceinline__ float slope_of(float lb, float ub) {
    float s = (ub - lb * NEG_SLOPE) / (ub - lb);
    if (!(s == s)) s = 0.f;
    return s;
}
__device__ __forceinline__ float uslope_of(float lb, float ub) {
    const bool below = (ub <= 0.f), above = (lb >= 0.f);
    return (!(below || above)) ? slope_of(lb, ub) : (below ? NEG_SLOPE : 1.f);
}
__device__ __forceinline__ float lslope_of(float lb, float ub, float raw) {
    const float alpha = 1.f / (1.f + expf(-raw));
    const bool below = (ub <= 0.f), above = (lb >= 0.f);
    const bool crossing = !(below || above);
    const float v1 = below ? NEG_SLOPE : 1.f;
    const float v2 = crossing ? NEG_SLOPE : v1;
    return alpha * v1 + (1.f - alpha) * v2;
}

// ---------------------------------------------------------------------------
// finish_fast, grid 18 (gemm zeroed floats [0, TAIL2)):
//  block 0:      zero tail floats [TAIL2, U_INT), set uslope diag j=4095
//  blocks 1..16: scattered diag writes: lslope all j, uslope j<4095
//  block 17:     uintercept row
// ---------------------------------------------------------------------------
__global__ __launch_bounds__(256)
void finish_fast(const float* __restrict__ S, const float* __restrict__ U,
                 const float* __restrict__ cj, const float* __restrict__ ra,
                 float* __restrict__ out) {
    const int b = blockIdx.x;
    const int t = threadIdx.x;
    if (b == 0) {
        f32x4* p = (f32x4*)(out + TAIL2);
#pragma unroll
        for (int q = 0; q < 4; ++q) {
            const int i4 = t + q * 256;
            f32x4 z = (f32x4){0.f, 0.f, 0.f, 0.f};
            if (i4 == 1023) {
                float lb, ub;
                get_lub(4095, S, U, cj, lb, ub);
                z[3] = uslope_of(lb, ub);   // U_DIAG + 4095*4097 == U_INT-1
            }
            __builtin_nontemporal_store(z, &p[i4]);
        }
    } else if (b <= 16) {
        const int j = (b - 1) * 256 + t;
        float lb, ub;
        get_lub(j, S, U, cj, lb, ub);
        out[(size_t)j * (NN + 1)] = lslope_of(lb, ub, ra[j]);
        if (j < 4095)
            out[U_DIAG + (size_t)j * (NN + 1)] = uslope_of(lb, ub);
    } else {
#pragma unroll
        for (int q = 0; q < 16; ++q) {
            const int j = t + q * 256;
            float lb, ub;
            get_lub(j, S, U, cj, lb, ub);
            const bool below = (ub <= 0.f), above = (lb >= 0.f);
            const bool crossing = !(below || above);
            out[U_INT + j] = crossing ? (1.f - slope_of(lb, ub)) * ub : 0.f;
        }
    }
}

// ---------------------------------------------------------------------------
// finish_slow, grid 4114 (fallback: Ah/Bt lived in out[0,64MB); gemm zeroed
// [L_INT, TAIL0)): R5 structure.
// ---------------------------------------------------------------------------
__global__ __launch_bounds__(256)
void finish_slow(const float* __restrict__ S, const float* __restrict__ U,
                 const float* __restrict__ cj, const float* __restrict__ ra,
                 float* __restrict__ out) {
    const int b = blockIdx.x;
    const int t = threadIdx.x;
    if (b < 4096) {
        const int j = b;
        float lb, ub;
        get_lub(j, S, U, cj, lb, ub);
        const float ls = lslope_of(lb, ub, ra[j]);
        f32x4* rowp = (f32x4*)(out + (size_t)j * NN);
        const int dq = j >> 2, dr = j & 3;
#pragma unroll
        for (int q = 0; q < 4; ++q) {
            const int i4 = t + q * 256;
            f32x4 z = (f32x4){0.f, 0.f, 0.f, 0.f};
            if (i4 == dq) z[dr] = ls;
            __builtin_nontemporal_store(z, &rowp[i4]);
        }
    } else if (b < 4112) {
        const int j = (b - 4096) * 256 + t;
        if (j < 4095) {
            float lb, ub;
            get_lub(j, S, U, cj, lb, ub);
            out[U_DIAG + (size_t)j * NN + j] = uslope_of(lb, ub);
        }
    } else if (b == 4112) {
        f32x4* p = (f32x4*)(out + TAIL0);
#pragma unroll
        for (int q = 0; q < 4; ++q) {
            const int i4 = t + q * 256;
            f32x4 z = (f32x4){0.f, 0.f, 0.f, 0.f};
            if (i4 == 1023) {
                float lb, ub;
                get_lub(4095, S, U, cj, lb, ub);
                z[3] = uslope_of(lb, ub);
            }
            __builtin_nontemporal_store(z, &p[i4]);
        }
    } else {
#pragma unroll
        for (int q = 0; q < 16; ++q) {
            const int j = t + q * 256;
            float lb, ub;
            get_lub(j, S, U, cj, lb, ub);
            const bool below = (ub <= 0.f), above = (lb >= 0.f);
            const bool crossing = !(below || above);
            out[U_INT + j] = crossing ? (1.f - slope_of(lb, ub)) * ub : 0.f;
        }
    }
}

extern "C" void kernel_launch(void* const* d_in, const int* in_sizes, int n_in,
                              void* d_out, int out_size, void* d_ws, size_t ws_size,
                              hipStream_t stream) {
    const float* lb0 = (const float*)d_in[0];
    const float* ub0 = (const float*)d_in[1];
    const float* W1  = (const float*)d_in[2];
    const float* b1  = (const float*)d_in[3];
    const float* W2  = (const float*)d_in[4];
    const float* b2  = (const float*)d_in[5];
    const float* ra  = (const float*)d_in[6];
    float* out = (float*)d_out;

    float* S  = (float*)d_ws;   // [N] zeroed by prep
    float* U  = S + NN;         // [N] zeroed by prep
    float* cj = U + NN;         // [N]

    const size_t need = 3 * (size_t)NN * sizeof(float)
                      + 2 * (size_t)NN * NN * sizeof(_Float16);
    const bool fast = ws_size >= need;   // ws_size is constant per session

    if (fast) {
        // Ah/Bt in d_ws -> gemm may zero-fill the whole diag area of d_out
        _Float16* Ah = (_Float16*)(cj + NN);
        _Float16* Bt = Ah + (size_t)NN * NN;
        prep<<<dim3(8192), dim3(256), 0, stream>>>(W2, W1, b1, b2, Ah, Bt, cj, S, U);
        gemm_SU<2><<<dim3(1024), dim3(256), 0, stream>>>(Ah, Bt, lb0, ub0, S, U,
                                                         (f32x4*)out);
        finish_fast<<<dim3(18), dim3(256), 0, stream>>>(S, U, cj, ra, out);
    } else {
        // fallback: Ah/Bt in d_out's first 64 MB (R5 layout)
        _Float16* Ah = (_Float16*)d_out;
        _Float16* Bt = Ah + (size_t)NN * NN;
        prep<<<dim3(8192), dim3(256), 0, stream>>>(W2, W1, b1, b2, Ah, Bt, cj, S, U);
        gemm_SU<4><<<dim3(1024), dim3(256), 0, stream>>>(Ah, Bt, lb0, ub0, S, U,
                                                         (f32x4*)(out + L_INT));
        finish_slow<<<dim3(4114), dim3(256), 0, stream>>>(S, U, cj, ra, out);
    }
}